// Round 1
// baseline (44.367 us; speedup 1.0000x reference)
//
#include <hip/hip_runtime.h>
#include <math.h>

#define BS 8192
#define D  1024

// ---------------------------------------------------------------------------
// Kernel 1: per-row reductions. One block per row, 256 threads, float4 loads
// (256 * 16B = 4 KB = one row of 1024 f32). Computes
//   wu  = sum_d w*u
//   wz  = sum_d w*z
//   w2  = sum_d w*w
// ---------------------------------------------------------------------------
__global__ __launch_bounds__(256) void rowreduce_kernel(
    const float* __restrict__ z, const float* __restrict__ w,
    const float* __restrict__ u,
    float* __restrict__ wu_out, float* __restrict__ wz_out,
    float* __restrict__ w2_out)
{
    const int row = blockIdx.x;
    const int t   = threadIdx.x;
    const size_t base = (size_t)row * D;
    const float4 zv = ((const float4*)(z + base))[t];
    const float4 wv = ((const float4*)(w + base))[t];
    const float4 uv = ((const float4*)(u + base))[t];

    float wu = wv.x*uv.x + wv.y*uv.y + wv.z*uv.z + wv.w*uv.w;
    float wz = wv.x*zv.x + wv.y*zv.y + wv.z*zv.z + wv.w*zv.w;
    float w2 = wv.x*wv.x + wv.y*wv.y + wv.z*wv.z + wv.w*wv.w;

    // wave-64 butterfly-less down-reduce
    #pragma unroll
    for (int off = 32; off > 0; off >>= 1) {
        wu += __shfl_down(wu, off, 64);
        wz += __shfl_down(wz, off, 64);
        w2 += __shfl_down(w2, off, 64);
    }
    __shared__ float swu[4], swz[4], sw2[4];
    const int wid = t >> 6, lane = t & 63;
    if (lane == 0) { swu[wid] = wu; swz[wid] = wz; sw2[wid] = w2; }
    __syncthreads();
    if (t == 0) {
        float a = 0.f, bb = 0.f, c = 0.f;
        #pragma unroll
        for (int i = 0; i < 4; ++i) { a += swu[i]; bb += swz[i]; c += sw2[i]; }
        wu_out[row] = a; wz_out[row] = bb; w2_out[row] = c;
    }
}

// ---------------------------------------------------------------------------
// Kernel 2: deterministic global sum of the 8192 per-row w2 values -> gw2.
// Single block of 1024 threads; each sums 8 values, then wave+LDS reduce.
// (Deterministic — no float atomics, so replays are bit-identical.)
// ---------------------------------------------------------------------------
__global__ __launch_bounds__(1024) void gsum_kernel(
    const float* __restrict__ w2_row, float* __restrict__ gw2)
{
    const int t = threadIdx.x;
    float s = 0.f;
    #pragma unroll
    for (int i = 0; i < BS / 1024; ++i) s += w2_row[t + i * 1024];
    #pragma unroll
    for (int off = 32; off > 0; off >>= 1) s += __shfl_down(s, off, 64);
    __shared__ float sm[16];
    const int wid = t >> 6, lane = t & 63;
    if (lane == 0) sm[wid] = s;
    __syncthreads();
    if (t == 0) {
        float tot = 0.f;
        #pragma unroll
        for (int i = 0; i < 16; ++i) tot += sm[i];
        *gw2 = tot;
    }
}

// ---------------------------------------------------------------------------
// Kernel 3: finalize. Per-row scalars recomputed by every thread (cheap,
// scalar-cache broadcast), then elementwise z_new; thread 0 writes log_det.
//   m      = -1 + softplus(wu)
//   coef   = (m - wu) / sqrt(gw2)
//   inner  = wz + b
//   tnh    = tanh(inner)
//   z_new  = z + tnh * (u + coef * w)
//   s      = wu + coef * row_w2         ( = sum_d w * u_hat )
//   inner2 = inner + tnh * s            ( = sum_d w * z_new + b )
//   log_det= log|1 + (1 - tanh(inner2)^2) * s|
// ---------------------------------------------------------------------------
__global__ __launch_bounds__(256) void finalize_kernel(
    const float* __restrict__ z, const float* __restrict__ w,
    const float* __restrict__ u, const float* __restrict__ b,
    const float* __restrict__ wu_a, const float* __restrict__ wz_a,
    const float* __restrict__ w2_a, const float* __restrict__ gw2,
    float* __restrict__ zout, float* __restrict__ ldout)
{
    const int row = blockIdx.x;
    const int t   = threadIdx.x;

    const float wu   = wu_a[row];
    const float wz   = wz_a[row];
    const float rw2  = w2_a[row];
    const float wnrm = sqrtf(*gw2);

    const float inner = wz + b[row];
    const float tnh   = tanhf(inner);
    // numerically stable softplus
    const float sp    = (wu > 0.f) ? (wu + log1pf(expf(-wu))) : log1pf(expf(wu));
    const float coef  = (-1.f + sp - wu) / wnrm;

    const size_t base = (size_t)row * D;
    const float4 zv = ((const float4*)(z + base))[t];
    const float4 wv = ((const float4*)(w + base))[t];
    const float4 uv = ((const float4*)(u + base))[t];
    float4 o;
    o.x = fmaf(tnh, fmaf(coef, wv.x, uv.x), zv.x);
    o.y = fmaf(tnh, fmaf(coef, wv.y, uv.y), zv.y);
    o.z = fmaf(tnh, fmaf(coef, wv.z, uv.z), zv.z);
    o.w = fmaf(tnh, fmaf(coef, wv.w, uv.w), zv.w);
    ((float4*)(zout + base))[t] = o;

    if (t == 0) {
        const float s      = fmaf(coef, rw2, wu);
        const float inner2 = fmaf(tnh, s, inner);
        const float th2    = tanhf(inner2);
        const float hp     = 1.f - th2 * th2;
        ldout[row] = logf(fabsf(fmaf(hp, s, 1.f)));
    }
}

extern "C" void kernel_launch(void* const* d_in, const int* in_sizes, int n_in,
                              void* d_out, int out_size, void* d_ws, size_t ws_size,
                              hipStream_t stream) {
    const float* z = (const float*)d_in[0];
    const float* w = (const float*)d_in[1];
    const float* u = (const float*)d_in[2];
    const float* b = (const float*)d_in[3];

    float* out   = (float*)d_out;
    float* zout  = out;               // [BS, D]
    float* ldout = out + (size_t)BS * D;  // [BS]

    float* ws   = (float*)d_ws;
    float* wu_a = ws;            // [BS]
    float* wz_a = ws + BS;       // [BS]
    float* w2_a = ws + 2 * BS;   // [BS]
    float* gw2  = ws + 3 * BS;   // [1]

    rowreduce_kernel<<<BS, 256, 0, stream>>>(z, w, u, wu_a, wz_a, w2_a);
    gsum_kernel<<<1, 1024, 0, stream>>>(w2_a, gw2);
    finalize_kernel<<<BS, 256, 0, stream>>>(z, w, u, b, wu_a, wz_a, w2_a, gw2,
                                            zout, ldout);
}

// Round 3
// 33.179 us; speedup vs baseline: 1.3372x; 1.3372x over previous
//
#include <hip/hip_runtime.h>
#include <math.h>

#define BS 8192
#define D  1024

// ---------------------------------------------------------------------------
// Kernel 1: global sum of w^2, phase 1. 2048 blocks x 256 threads, each
// thread 4x float4 grid-stride. Block partial -> partials[blockIdx.x].
// Reads only w (32 MB).
// ---------------------------------------------------------------------------
#define WS_BLK 2048
__global__ __launch_bounds__(256) void wsum_kernel(
    const float* __restrict__ w, float* __restrict__ partials)
{
    const int t   = threadIdx.x;
    const int gid = blockIdx.x * 256 + t;
    const float4* w4 = (const float4*)w;
    float s = 0.f;
#pragma unroll
    for (int i = 0; i < 4; ++i) {
        const float4 v = w4[gid + i * (WS_BLK * 256)];
        s += v.x*v.x + v.y*v.y + v.z*v.z + v.w*v.w;
    }
#pragma unroll
    for (int off = 32; off > 0; off >>= 1) s += __shfl_down(s, off, 64);
    __shared__ float sm[4];
    if ((t & 63) == 0) sm[t >> 6] = s;
    __syncthreads();
    if (t == 0) partials[blockIdx.x] = sm[0] + sm[1] + sm[2] + sm[3];
}

// ---------------------------------------------------------------------------
// Kernel 2: deterministic sum of the 2048 partials -> wnrm = sqrt(sum w^2).
// ---------------------------------------------------------------------------
__global__ __launch_bounds__(1024) void gsum_kernel(
    const float* __restrict__ partials, float* __restrict__ wnrm)
{
    const int t = threadIdx.x;
    float s = partials[t] + partials[t + 1024];
#pragma unroll
    for (int off = 32; off > 0; off >>= 1) s += __shfl_down(s, off, 64);
    __shared__ float sm[16];
    if ((t & 63) == 0) sm[t >> 6] = s;
    __syncthreads();
    if (t == 0) {
        float tot = 0.f;
#pragma unroll
        for (int i = 0; i < 16; ++i) tot += sm[i];
        *wnrm = sqrtf(tot);
    }
}

// ---------------------------------------------------------------------------
// Kernel 3: fused per-row reduce + finalize. One block per row, 256 threads,
// row held in registers (3x float4/thread). No second pass over HBM.
//   wu = sum w*u ; wz = sum w*z ; w2 = sum w*w   (block reduce, broadcast)
//   m = -1 + softplus(wu); coef = (m - wu)/wnrm
//   inner = wz + b; tnh = tanh(inner)
//   z_new = z + tnh*(u + coef*w)
//   s = wu + coef*w2 ; inner2 = inner + tnh*s          (identity, no re-reduce)
//   log_det = log|1 + (1 - tanh(inner2)^2) * s|
// ---------------------------------------------------------------------------
__global__ __launch_bounds__(256) void fused_row_kernel(
    const float* __restrict__ z, const float* __restrict__ w,
    const float* __restrict__ u, const float* __restrict__ b,
    const float* __restrict__ wnrm_p,
    float* __restrict__ zout, float* __restrict__ ldout)
{
    const int row = blockIdx.x;
    const int t   = threadIdx.x;
    const size_t base = (size_t)row * D;

    const float4 zv = ((const float4*)(z + base))[t];
    const float4 wv = ((const float4*)(w + base))[t];
    const float4 uv = ((const float4*)(u + base))[t];

    float wu = wv.x*uv.x + wv.y*uv.y + wv.z*uv.z + wv.w*uv.w;
    float wz = wv.x*zv.x + wv.y*zv.y + wv.z*zv.z + wv.w*zv.w;
    float w2 = wv.x*wv.x + wv.y*wv.y + wv.z*wv.z + wv.w*wv.w;

#pragma unroll
    for (int off = 32; off > 0; off >>= 1) {
        wu += __shfl_down(wu, off, 64);
        wz += __shfl_down(wz, off, 64);
        w2 += __shfl_down(w2, off, 64);
    }
    __shared__ float swu[4], swz[4], sw2[4];
    if ((t & 63) == 0) { const int wi = t >> 6; swu[wi] = wu; swz[wi] = wz; sw2[wi] = w2; }
    __syncthreads();
    // every thread sums the 4 wave partials (LDS broadcast reads)
    wu = swu[0] + swu[1] + swu[2] + swu[3];
    wz = swz[0] + swz[1] + swz[2] + swz[3];
    w2 = sw2[0] + sw2[1] + sw2[2] + sw2[3];

    const float wnrm  = *wnrm_p;
    const float inner = wz + b[row];
    const float tnh   = tanhf(inner);
    const float sp    = (wu > 0.f) ? (wu + log1pf(expf(-wu))) : log1pf(expf(wu));
    const float coef  = (-1.f + sp - wu) / wnrm;
    const float tc    = tnh * coef;

    float4 o;
    o.x = fmaf(tnh, uv.x, fmaf(tc, wv.x, zv.x));
    o.y = fmaf(tnh, uv.y, fmaf(tc, wv.y, zv.y));
    o.z = fmaf(tnh, uv.z, fmaf(tc, wv.z, zv.z));
    o.w = fmaf(tnh, uv.w, fmaf(tc, wv.w, zv.w));
    ((float4*)(zout + base))[t] = o;

    if (t == 0) {
        const float s      = fmaf(coef, w2, wu);
        const float inner2 = fmaf(tnh, s, inner);
        const float th2    = tanhf(inner2);
        const float hp     = 1.f - th2 * th2;
        ldout[row] = logf(fabsf(fmaf(hp, s, 1.f)));
    }
}

extern "C" void kernel_launch(void* const* d_in, const int* in_sizes, int n_in,
                              void* d_out, int out_size, void* d_ws, size_t ws_size,
                              hipStream_t stream) {
    const float* z = (const float*)d_in[0];
    const float* w = (const float*)d_in[1];
    const float* u = (const float*)d_in[2];
    const float* b = (const float*)d_in[3];

    float* out   = (float*)d_out;
    float* zout  = out;                    // [BS, D]
    float* ldout = out + (size_t)BS * D;   // [BS]

    float* partials = (float*)d_ws;        // [WS_BLK]
    float* wnrm     = partials + WS_BLK;   // [1]

    wsum_kernel<<<WS_BLK, 256, 0, stream>>>(w, partials);
    gsum_kernel<<<1, 1024, 0, stream>>>(partials, wnrm);
    fused_row_kernel<<<BS, 256, 0, stream>>>(z, w, u, b, wnrm, zout, ldout);
}